// Round 21
// baseline (57.812 us; speedup 1.0000x reference)
//
#include <hip/hip_runtime.h>

#define E  1024
#define H  64
#define BB 8
#define TT 2048

typedef __attribute__((ext_vector_type(8)))  short bf16x8;
typedef __attribute__((ext_vector_type(4)))  float f32x4;
typedef __attribute__((ext_vector_type(16))) float f32x16;
typedef __attribute__((ext_vector_type(8)))  short short8;
typedef __attribute__((ext_vector_type(4)))  short short4v;
typedef __attribute__((ext_vector_type(4)))  unsigned u32x4;

__device__ __forceinline__ short f2bf(float f) {
    union { float f; unsigned u; } v; v.f = f;
    unsigned r = v.u + 0x7FFFu + ((v.u >> 16) & 1u);   // RNE
    return (short)(r >> 16);
}

// fast 2^x via the HW transcendental (no HIP __exp2f intrinsic exists)
__device__ __forceinline__ float fexp2(float x) {
    float r;
    asm("v_exp_f32 %0, %1" : "=v"(r) : "v"(x));
    return r;
}

__device__ __forceinline__ bf16x8 asbf(u32x4 v) {
    bf16x8 r;
    __builtin_memcpy(&r, &v, 16);
    return r;
}

// 8 fp32 (as 2x u32x4) -> bf16x8 via 4x v_cvt_pk_bf16_f32
__device__ __forceinline__ bf16x8 cvt8u(u32x4 a, u32x4 b) {
    unsigned w0, w1, w2, w3;
    float a0 = __uint_as_float(a[0]), a1 = __uint_as_float(a[1]);
    float a2 = __uint_as_float(a[2]), a3 = __uint_as_float(a[3]);
    float b0 = __uint_as_float(b[0]), b1 = __uint_as_float(b[1]);
    float b2 = __uint_as_float(b[2]), b3 = __uint_as_float(b[3]);
    asm("v_cvt_pk_bf16_f32 %0, %1, %2" : "=v"(w0) : "v"(a0), "v"(a1));
    asm("v_cvt_pk_bf16_f32 %0, %1, %2" : "=v"(w1) : "v"(a2), "v"(a3));
    asm("v_cvt_pk_bf16_f32 %0, %1, %2" : "=v"(w2) : "v"(b0), "v"(b1));
    asm("v_cvt_pk_bf16_f32 %0, %1, %2" : "=v"(w3) : "v"(b2), "v"(b3));
    u32x4 u = {w0, w1, w2, w3};
    return asbf(u);
}

// forced 16B global load: volatile asm with distinct "=v" outputs cannot be
// serialized by the register allocator (the v7/v8/v12 failure mode)
#define GLD(dst, p) \
    asm volatile("global_load_dwordx4 %0, %1, off" \
                 : "=v"(dst) : "v"((unsigned long long)(p)) : "memory")

// ---- pack W into per-K-step, frag-ordered CONTIGUOUS blocks (16x16x32 B) ----
__global__ __launch_bounds__(256)
void pack_w3(const float* __restrict__ Wq, const float* __restrict__ Wk,
             const float* __restrict__ Wv, short* __restrict__ Wb3)
{
    const int t  = blockIdx.x * 256 + threadIdx.x;   // 24576 total
    const int l  = t & 63;
    const int f  = (t >> 6) % 12;
    const int sc = t / 768;                          // k32-chunk 0..31
    const int n  = f * 16 + (l & 15);
    const int m  = n >> 6, nn = n & 63;
    const float* W = (m == 0) ? Wq : (m == 1 ? Wk : Wv);
    const int k0 = sc * 32 + ((l >> 4) << 3);
    short8 o;
    #pragma unroll
    for (int j = 0; j < 8; ++j) o[j] = f2bf(W[(k0 + j) * 64 + nn]);
    *(short8*)&Wb3[(size_t)t * 8] = o;
}

// ---- proj v13: asm-batched loads, 2-stage counted-vmcnt pipeline, no LDS ----
// 256 blocks x 256 thr; block = 64 rows x 192 cols; wave (rg, cg) = 32 rows
// x 96 cols, acc 48 VGPR. Per K32-step: 4 A-loads (fp32 -> cvt8) + 6 B-frags,
// ALL via volatile asm global_load_dwordx4 (distinct live outputs -> RA must
// pipeline); stage s+1 issued before compute(s); s_waitcnt vmcnt(10) keeps
// next stage's 10 loads in flight; sched_barrier(0) fences MFMA hoisting.
__global__ __attribute__((amdgpu_waves_per_eu(1, 2))) __launch_bounds__(256)
void proj_v13(const float* __restrict__ x, const short* __restrict__ Wb3,
              short* __restrict__ q, short* __restrict__ k, short* __restrict__ vt)
{
    const int t  = threadIdx.x;
    const int l  = t & 63;
    const int w  = t >> 6;
    const int rg = w & 1, cg = w >> 1;   // 2 row-groups x 2 col-groups
    const int l15 = l & 15, g = l >> 4;
    const long row0 = (long)blockIdx.x * 64;

    f32x4 acc[2][6] = {};

    // A: frag row = row0 + rg*32 + rt*16 + l15, k = s*32 + g*8 (+4)
    const float* ax0 = x + (row0 + rg * 32 + l15) * E + g * 8;
    const float* ax1 = x + (row0 + rg * 32 + 16 + l15) * E + g * 8;
    // B: frag fi of col-group cg at step s: Wb3 + ((s*12 + cg*6 + fi)*64 + l)*8
    const short* bp = Wb3 + ((size_t)(cg * 6) * 64 + l) * 8;

    // stage registers (named; 20 x u32x4 = 80 VGPR live across the pipeline)
    u32x4 xA0, xA1, xA2, xA3, yA0, yA1, yA2, yA3, yA4, yA5;
    u32x4 xB0, xB1, xB2, xB3, yB0, yB1, yB2, yB3, yB4, yB5;

#define ISSUE_A(s) do { \
    GLD(xA0, ax0 + (s) * 32); GLD(xA1, ax0 + (s) * 32 + 4); \
    GLD(xA2, ax1 + (s) * 32); GLD(xA3, ax1 + (s) * 32 + 4); \
    GLD(yA0, bp + ((size_t)(s) * 12 + 0) * 512); \
    GLD(yA1, bp + ((size_t)(s) * 12 + 1) * 512); \
    GLD(yA2, bp + ((size_t)(s) * 12 + 2) * 512); \
    GLD(yA3, bp + ((size_t)(s) * 12 + 3) * 512); \
    GLD(yA4, bp + ((size_t)(s) * 12 + 4) * 512); \
    GLD(yA5, bp + ((size_t)(s) * 12 + 5) * 512); \
} while (0)
#define ISSUE_B(s) do { \
    GLD(xB0, ax0 + (s) * 32); GLD(xB1, ax0 + (s) * 32 + 4); \
    GLD(xB2, ax1 + (s) * 32); GLD(xB3, ax1 + (s) * 32 + 4); \
    GLD(yB0, bp + ((size_t)(s) * 12 + 0) * 512); \
    GLD(yB1, bp + ((size_t)(s) * 12 + 1) * 512); \
    GLD(yB2, bp + ((size_t)(s) * 12 + 2) * 512); \
    GLD(yB3, bp + ((size_t)(s) * 12 + 3) * 512); \
    GLD(yB4, bp + ((size_t)(s) * 12 + 4) * 512); \
    GLD(yB5, bp + ((size_t)(s) * 12 + 5) * 512); \
} while (0)
#define COMPUTE(X0, X1, X2, X3, Y0, Y1, Y2, Y3, Y4, Y5) do { \
    bf16x8 af0 = cvt8u(X0, X1); \
    bf16x8 af1 = cvt8u(X2, X3); \
    acc[0][0] = __builtin_amdgcn_mfma_f32_16x16x32_bf16(af0, asbf(Y0), acc[0][0], 0, 0, 0); \
    acc[1][0] = __builtin_amdgcn_mfma_f32_16x16x32_bf16(af1, asbf(Y0), acc[1][0], 0, 0, 0); \
    acc[0][1] = __builtin_amdgcn_mfma_f32_16x16x32_bf16(af0, asbf(Y1), acc[0][1], 0, 0, 0); \
    acc[1][1] = __builtin_amdgcn_mfma_f32_16x16x32_bf16(af1, asbf(Y1), acc[1][1], 0, 0, 0); \
    acc[0][2] = __builtin_amdgcn_mfma_f32_16x16x32_bf16(af0, asbf(Y2), acc[0][2], 0, 0, 0); \
    acc[1][2] = __builtin_amdgcn_mfma_f32_16x16x32_bf16(af1, asbf(Y2), acc[1][2], 0, 0, 0); \
    acc[0][3] = __builtin_amdgcn_mfma_f32_16x16x32_bf16(af0, asbf(Y3), acc[0][3], 0, 0, 0); \
    acc[1][3] = __builtin_amdgcn_mfma_f32_16x16x32_bf16(af1, asbf(Y3), acc[1][3], 0, 0, 0); \
    acc[0][4] = __builtin_amdgcn_mfma_f32_16x16x32_bf16(af0, asbf(Y4), acc[0][4], 0, 0, 0); \
    acc[1][4] = __builtin_amdgcn_mfma_f32_16x16x32_bf16(af1, asbf(Y4), acc[1][4], 0, 0, 0); \
    acc[0][5] = __builtin_amdgcn_mfma_f32_16x16x32_bf16(af0, asbf(Y5), acc[0][5], 0, 0, 0); \
    acc[1][5] = __builtin_amdgcn_mfma_f32_16x16x32_bf16(af1, asbf(Y5), acc[1][5], 0, 0, 0); \
} while (0)

    ISSUE_A(0);
    for (int s2 = 0; s2 < 16; ++s2) {
        const int s = 2 * s2;
        // even half: issue s+1 into stage B, wait stage A (s), compute s
        ISSUE_B(s + 1);
        asm volatile("s_waitcnt vmcnt(10)" ::: "memory");
        __builtin_amdgcn_sched_barrier(0);
        COMPUTE(xA0, xA1, xA2, xA3, yA0, yA1, yA2, yA3, yA4, yA5);
        // odd half: issue s+2 into stage A (if any), wait stage B, compute s+1
        if (s2 < 15) {
            ISSUE_A(s + 2);
            asm volatile("s_waitcnt vmcnt(10)" ::: "memory");
        } else {
            asm volatile("s_waitcnt vmcnt(0)" ::: "memory");
        }
        __builtin_amdgcn_sched_barrier(0);
        COMPUTE(xB0, xB1, xB2, xB3, yB0, yB1, yB2, yB3, yB4, yB5);
    }

    // ---- epilogue: C frag (col=l15, row=g*4+r) per (rt, fi) ----
    #pragma unroll
    for (int rt = 0; rt < 2; ++rt) {
        const long trow = row0 + rg * 32 + rt * 16 + g * 4;
        const long bb   = trow >> 11;
        const int  t0   = (int)(trow & 2047);
        #pragma unroll
        for (int fi = 0; fi < 6; ++fi) {
            const int n = cg * 96 + fi * 16 + l15;
            const int m = n >> 6;
            const int h = n & 63;
            if (m == 2) {
                short4v pkt;
                #pragma unroll
                for (int r = 0; r < 4; ++r) pkt[r] = f2bf(acc[rt][fi][r]);
                *(short4v*)&vt[(bb * 64 + h) * TT + t0] = pkt;
            } else {
                short* base = (m == 0) ? q : k;
                // fold 1/sqrt(H) AND log2(e) into q -> softmax uses exp2
                const float sc = (m == 0) ? (0.125f * 1.44269504f) : 1.0f;
                #pragma unroll
                for (int r = 0; r < 4; ++r)
                    base[(trow + r) * 64 + h] = f2bf(acc[rt][fi][r] * sc);
            }
        }
    }
#undef ISSUE_A
#undef ISSUE_B
#undef COMPUTE
}

// ---- 32x32 swapped-QK^T flash attention (unchanged) ----
__global__ __launch_bounds__(512)
void attn_v8(const short* __restrict__ qg,
             const short* __restrict__ kg,
             const short* __restrict__ vtg,
             float* __restrict__ out)
{
    __shared__ float Op[8][32][66];
    __shared__ float Ml[8][32][2];

    const int t   = threadIdx.x;
    const int L   = t & 63;
    const int w   = t >> 6;
    const int bid = blockIdx.x;
    const int b   = bid & 7;
    const int pr  = bid >> 3;
    const int l31 = L & 31, hi = L >> 5;

    const int stA = pr, stB = 63 - pr;
    const int nA = stA + 1;
    int WA = (8 * nA + 32) / 65;
    WA = WA < 1 ? 1 : (WA > 7 ? 7 : WA);
    const int WB = 8 - WA;

    const bool isB  = (w >= WA);
    const int  st   = isB ? stB : stA;
    const int  q0   = st * 32;
    const int  strd = isB ? WB : WA;
    const int  c0   = isB ? (w - WA) : w;

    bf16x8 qf[4];
    {
        const short* qp = qg + ((long)b * TT + q0 + l31) * 64 + hi * 8;
        qf[0] = *(const bf16x8*)(qp);
        qf[1] = *(const bf16x8*)(qp + 16);
        qf[2] = *(const bf16x8*)(qp + 32);
        qf[3] = *(const bf16x8*)(qp + 48);
    }

    f32x16 o0 = {}, o1 = {};
    float mrun = -1e30f, lrun = 0.f;

    const short* kbase = kg  + ((long)b * TT + l31) * 64 + hi * 8;
    const short* vbase = vtg + ((long)b * 64 + l31) * TT + hi * 8;

    for (int ci = c0; ci <= st; ci += strd) {
        const int kvs = ci * 32;
        const short* kp = kbase + (long)kvs * 64;
        bf16x8 kf0 = *(const bf16x8*)(kp);
        bf16x8 kf1 = *(const bf16x8*)(kp + 16);
        bf16x8 kf2 = *(const bf16x8*)(kp + 32);
        bf16x8 kf3 = *(const bf16x8*)(kp + 48);
        const short* vp = vbase + kvs;
        bf16x8 vf00 = *(const bf16x8*)(vp);
        bf16x8 vf01 = *(const bf16x8*)(vp + 16);
        bf16x8 vf10 = *(const bf16x8*)(vp + 32 * TT);
        bf16x8 vf11 = *(const bf16x8*)(vp + 32 * TT + 16);

        f32x16 s = {};
        __builtin_amdgcn_s_setprio(1);
        s = __builtin_amdgcn_mfma_f32_32x32x16_bf16(kf0, qf[0], s, 0, 0, 0);
        s = __builtin_amdgcn_mfma_f32_32x32x16_bf16(kf1, qf[1], s, 0, 0, 0);
        s = __builtin_amdgcn_mfma_f32_32x32x16_bf16(kf2, qf[2], s, 0, 0, 0);
        s = __builtin_amdgcn_mfma_f32_32x32x16_bf16(kf3, qf[3], s, 0, 0, 0);
        __builtin_amdgcn_s_setprio(0);

        if (kvs == q0) {
            #pragma unroll
            for (int r = 0; r < 16; ++r) {
                const int crow = (r & 3) + 8 * (r >> 2) + 4 * hi;
                if (crow > l31) s[r] = -1e30f;
            }
        }
        float m01 = fmaxf(s[0], s[1]),   m23 = fmaxf(s[2], s[3]);
        float m45 = fmaxf(s[4], s[5]),   m67 = fmaxf(s[6], s[7]);
        float m89 = fmaxf(s[8], s[9]),   mab = fmaxf(s[10], s[11]);
        float mcd = fmaxf(s[12], s[13]), mef = fmaxf(s[14], s[15]);
        float mloc = fmaxf(fmaxf(fmaxf(m01, m23), fmaxf(m45, m67)),
                           fmaxf(fmaxf(m89, mab), fmaxf(mcd, mef)));
        mloc = fmaxf(mloc, __shfl_xor(mloc, 32));
        if (__any(mloc > mrun + 8.f)) {
            const float mnew = fmaxf(mrun, mloc);
            const float a = fexp2(mrun - mnew);
            mrun = mnew;
            lrun *= a;
            #pragma unroll
            for (int r = 0; r < 16; ++r) { o0[r] *= a; o1[r] *= a; }
        }
        #pragma unroll
        for (int r = 0; r < 16; ++r) s[r] = fexp2(s[r] - mrun);
        {
            float s01 = (s[0] + s[1]) + (s[2] + s[3]);
            float s23 = (s[4] + s[5]) + (s[6] + s[7]);
            float s45 = (s[8] + s[9]) + (s[10] + s[11]);
            float s67 = (s[12] + s[13]) + (s[14] + s[15]);
            float lsum = (s01 + s23) + (s45 + s67);
            lsum += __shfl_xor(lsum, 32);
            lrun += lsum;
        }
        unsigned wv[8];
        #pragma unroll
        for (int i = 0; i < 8; ++i)
            asm("v_cvt_pk_bf16_f32 %0, %1, %2" : "=v"(wv[i]) : "v"(s[2 * i]), "v"(s[2 * i + 1]));
        unsigned p00 = wv[0], p02 = wv[2];
        unsigned p01 = wv[1], p03 = wv[3];
        unsigned p10 = wv[4], p12 = wv[6];
        unsigned p11 = wv[5], p13 = wv[7];
        asm("v_permlane32_swap_b32 %0, %1" : "+v"(p00), "+v"(p02));
        asm("v_permlane32_swap_b32 %0, %1" : "+v"(p01), "+v"(p03));
        asm("v_permlane32_swap_b32 %0, %1" : "+v"(p10), "+v"(p12));
        asm("v_permlane32_swap_b32 %0, %1" : "+v"(p11), "+v"(p13));
        u32x4 pb0u = {p00, p01, p02, p03};
        u32x4 pb1u = {p10, p11, p12, p13};
        bf16x8 pb0, pb1;
        __builtin_memcpy(&pb0, &pb0u, 16);
        __builtin_memcpy(&pb1, &pb1u, 16);
        __builtin_amdgcn_s_setprio(1);
        o0 = __builtin_amdgcn_mfma_f32_32x32x16_bf16(vf00, pb0, o0, 0, 0, 0);
        o0 = __builtin_amdgcn_mfma_f32_32x32x16_bf16(vf01, pb1, o0, 0, 0, 0);
        o1 = __builtin_amdgcn_mfma_f32_32x32x16_bf16(vf10, pb0, o1, 0, 0, 0);
        o1 = __builtin_amdgcn_mfma_f32_32x32x16_bf16(vf11, pb1, o1, 0, 0, 0);
        __builtin_amdgcn_s_setprio(0);
    }

    #pragma unroll
    for (int r = 0; r < 16; ++r) {
        const int h = (r & 3) + 8 * (r >> 2) + 4 * hi;
        Op[w][l31][h]      = o0[r];
        Op[w][l31][32 + h] = o1[r];
    }
    if (hi == 0) {
        Ml[w][l31][0] = mrun;
        Ml[w][l31][1] = lrun;
    }
    __syncthreads();

    {
        const bool tb   = (w >= 4);
        const int  base = tb ? WA : 0;
        const int  cnt  = tb ? WB : WA;
        const long oq0  = (long)(tb ? stB : stA) * 32;
        #pragma unroll
        for (int rr = 0; rr < 8; ++rr) {
            const int row = (w & 3) * 8 + rr;
            float M = -1e30f;
            for (int j = 0; j < cnt; ++j)
                M = fmaxf(M, Ml[base + j][row][0]);
            float Ls = 0.f, val = 0.f;
            for (int j = 0; j < cnt; ++j) {
                const float a = fexp2(Ml[base + j][row][0] - M);
                Ls  += a * Ml[base + j][row][1];
                val += a * Op[base + j][row][L];
            }
            out[((long)b * TT + oq0 + row) * 64 + L] = val / Ls;
        }
    }
}

extern "C" void kernel_launch(void* const* d_in, const int* in_sizes, int n_in,
                              void* d_out, int out_size, void* d_ws, size_t ws_size,
                              hipStream_t stream)
{
    const float* x  = (const float*)d_in[0];
    const float* Wq = (const float*)d_in[1];
    const float* Wk = (const float*)d_in[2];
    const float* Wv = (const float*)d_in[3];
    float* out = (float*)d_out;

    const size_t n = (size_t)BB * TT * H;   // 1,048,576 per tensor
    short* q   = (short*)d_ws;
    short* k   = q + n;
    short* vt  = k + n;                     // V transposed: [B][H][T]
    short* Wb3 = vt + n;                    // 196,608 shorts

    pack_w3  <<<dim3(96),  256, 0, stream>>>(Wq, Wk, Wv, Wb3);
    proj_v13 <<<dim3(256), 256, 0, stream>>>(x, Wb3, q, k, vt);
    attn_v8  <<<dim3(256), 512, 0, stream>>>(q, k, vt, out);
}